// Round 2
// baseline (440.077 us; speedup 1.0000x reference)
//
#include <hip/hip_runtime.h>
#include <math.h>

#define TOKENS 16384
#define EXPERTS 64
#define DIM 2048
#define BETA 0.5f
#define EPSILON 0.05f
#define EPSN 1e-12f
#define LOGMASS 5.545177444479562f  // log(16384/64)

// ws layout (float offsets)
#define OFF_ENORM   0            // 64*2048
#define OFF_ENORMT  131072       // 2048*64
#define OFF_M       262144       // 64*64
#define OFF_LOGK    266240       // 16384*64
#define OFF_U       1314816      // 16384
#define OFF_V       1331200      // 64
#define OFF_PART    1331264      // 256*64*2
// total 1364032 floats = 5.46 MB

// out layout (float offsets): probs 0, sim 1048576, gram 2097152, gram_off 2101248

// ---------------- K1: normalize expert rows, write e_norm + e_normT ----------------
__global__ __launch_bounds__(256) void k1_norm_experts(const float* __restrict__ ex,
                                                       float* __restrict__ ws) {
  int j = blockIdx.x, t = threadIdx.x;
  const float4* row4 = (const float4*)(ex + (size_t)j * DIM);
  float4 v0 = row4[t];
  float4 v1 = row4[t + 256];
  float ss = v0.x*v0.x + v0.y*v0.y + v0.z*v0.z + v0.w*v0.w
           + v1.x*v1.x + v1.y*v1.y + v1.z*v1.z + v1.w*v1.w;
  #pragma unroll
  for (int m = 1; m < 64; m <<= 1) ss += __shfl_xor(ss, m);
  __shared__ float red[4];
  int wv = t >> 6, ln = t & 63;
  if (ln == 0) red[wv] = ss;
  __syncthreads();
  float tot = red[0] + red[1] + red[2] + red[3];
  float sc = 1.0f / fmaxf(sqrtf(tot), EPSN);
  float4 w0 = make_float4(v0.x*sc, v0.y*sc, v0.z*sc, v0.w*sc);
  float4 w1 = make_float4(v1.x*sc, v1.y*sc, v1.z*sc, v1.w*sc);
  float4* en4 = (float4*)(ws + OFF_ENORM + (size_t)j * DIM);
  en4[t] = w0;
  en4[t + 256] = w1;
  float* enT = ws + OFF_ENORMT;
  int c0 = t * 4, c1 = (t + 256) * 4;
  enT[(c0+0)*64 + j] = w0.x; enT[(c0+1)*64 + j] = w0.y;
  enT[(c0+2)*64 + j] = w0.z; enT[(c0+3)*64 + j] = w0.w;
  enT[(c1+0)*64 + j] = w1.x; enT[(c1+1)*64 + j] = w1.y;
  enT[(c1+2)*64 + j] = w1.z; enT[(c1+3)*64 + j] = w1.w;
}

// ---------------- K2: gram, gram_off, M = I - beta*gram_off ----------------
__global__ __launch_bounds__(256) void k2_gram(const float* __restrict__ wsr,
                                               float* __restrict__ ws,
                                               float* __restrict__ out) {
  __shared__ __align__(16) float ej[DIM];
  __shared__ float part[4][64];
  int j = blockIdx.x, t = threadIdx.x;
  const float4* en4 = (const float4*)(wsr + OFF_ENORM + (size_t)j * DIM);
  ((float4*)ej)[t] = en4[t];
  ((float4*)ej)[t + 256] = en4[t + 256];
  __syncthreads();
  const float* enT = wsr + OFF_ENORMT;
  int k = t & 63, q = t >> 6;
  float p = 0.0f;
  int c0 = q * 512;
  for (int c = c0; c < c0 + 512; ++c) p += ej[c] * enT[(size_t)c * 64 + k];
  part[q][k] = p;
  __syncthreads();
  if (t < 64) {
    float g = part[0][t] + part[1][t] + part[2][t] + part[3][t];
    out[2097152 + j*64 + t] = g;
    float go = fmaxf(g - (t == j ? 1.0f : 0.0f), 0.0f);
    out[2101248 + j*64 + t] = go;
    ws[OFF_M + j*64 + t] = (t == j ? 1.0f : 0.0f) - BETA * go;
  }
}

// ---------------- K3: fused sim + logK (64x64 tile GEMM, fp32) ----------------
__global__ __launch_bounds__(256) void k3_main(const float* __restrict__ x,
                                               const float* __restrict__ wsr,
                                               float* __restrict__ ws,
                                               float* __restrict__ out) {
  __shared__ __align__(16) float At[64 * 68];   // [kk][row], stride 68
  __shared__ __align__(16) float Bt[64 * 64];   // [kk][expert]
  __shared__ __align__(16) float Ml[64 * 64];   // M matrix
  __shared__ float scaleL[64];
  int t = threadIdx.x;
  int r0 = blockIdx.x << 6;
  int tr = t >> 4, tc = t & 15;

  const float4* Mw = (const float4*)(wsr + OFF_M);
  float4* Ml4 = (float4*)Ml;
  #pragma unroll
  for (int s = 0; s < 4; ++s) Ml4[s * 256 + t] = Mw[s * 256 + t];

  float acc[4][4] = {{0.f,0.f,0.f,0.f},{0.f,0.f,0.f,0.f},{0.f,0.f,0.f,0.f},{0.f,0.f,0.f,0.f}};
  float nsq[4] = {0.f, 0.f, 0.f, 0.f};
  const float* enT = wsr + OFF_ENORMT;

  for (int kc = 0; kc < DIM; kc += 64) {
    float4 bv[4], av[4];
    const float4* bsrc = (const float4*)(enT + (size_t)kc * 64);
    #pragma unroll
    for (int s = 0; s < 4; ++s) bv[s] = bsrc[s * 256 + t];
    #pragma unroll
    for (int s = 0; s < 4; ++s) {
      int row = tr + 16 * s;
      av[s] = *(const float4*)(x + (size_t)(r0 + row) * DIM + kc + (tc << 2));
      nsq[s] += av[s].x*av[s].x + av[s].y*av[s].y + av[s].z*av[s].z + av[s].w*av[s].w;
    }
    __syncthreads();
    float4* Bt4 = (float4*)Bt;
    #pragma unroll
    for (int s = 0; s < 4; ++s) {
      Bt4[s * 256 + t] = bv[s];
      int row = tr + 16 * s;
      int kb = tc << 2;
      At[(kb + 0) * 68 + row] = av[s].x;
      At[(kb + 1) * 68 + row] = av[s].y;
      At[(kb + 2) * 68 + row] = av[s].z;
      At[(kb + 3) * 68 + row] = av[s].w;
    }
    __syncthreads();
    #pragma unroll 8
    for (int kk = 0; kk < 64; ++kk) {
      float4 a = *(const float4*)&At[kk * 68 + (tr << 2)];
      float4 b = *(const float4*)&Bt[kk * 64 + (tc << 2)];
      acc[0][0] += a.x*b.x; acc[0][1] += a.x*b.y; acc[0][2] += a.x*b.z; acc[0][3] += a.x*b.w;
      acc[1][0] += a.y*b.x; acc[1][1] += a.y*b.y; acc[1][2] += a.y*b.z; acc[1][3] += a.y*b.w;
      acc[2][0] += a.z*b.x; acc[2][1] += a.z*b.y; acc[2][2] += a.z*b.z; acc[2][3] += a.z*b.w;
      acc[3][0] += a.w*b.x; acc[3][1] += a.w*b.y; acc[3][2] += a.w*b.z; acc[3][3] += a.w*b.w;
    }
  }
  __syncthreads();
  // row norms: reduce per-thread partial sumsq (cols == tc slice) across the 16 tc threads
  float* sq = Bt;  // reuse
  #pragma unroll
  for (int s = 0; s < 4; ++s) sq[tc * 64 + tr + 16 * s] = nsq[s];
  __syncthreads();
  if (t < 64) {
    float tot = 0.f;
    #pragma unroll
    for (int c = 0; c < 16; ++c) tot += sq[c * 64 + t];
    scaleL[t] = 1.0f / fmaxf(sqrtf(tot), EPSN);
  }
  __syncthreads();
  // sim = acc * scale; write global + LDS (reuse At as simL [row][68])
  float* simL = At;
  float* simOut = out + 1048576;
  #pragma unroll
  for (int i = 0; i < 4; ++i) {
    int row = (tr << 2) + i;
    float sc = scaleL[row];
    float4 sv = make_float4(acc[i][0]*sc, acc[i][1]*sc, acc[i][2]*sc, acc[i][3]*sc);
    *(float4*)&simL[row * 68 + (tc << 2)] = sv;
    *(float4*)(simOut + (size_t)(r0 + row) * 64 + (tc << 2)) = sv;
  }
  __syncthreads();
  // logK = (sim @ M) / eps
  float lk[4][4] = {{0.f,0.f,0.f,0.f},{0.f,0.f,0.f,0.f},{0.f,0.f,0.f,0.f},{0.f,0.f,0.f,0.f}};
  #pragma unroll 8
  for (int j = 0; j < 64; ++j) {
    float4 mj = *(const float4*)&Ml[j * 64 + (tc << 2)];
    float s0 = simL[((tr << 2) + 0) * 68 + j];
    float s1 = simL[((tr << 2) + 1) * 68 + j];
    float s2 = simL[((tr << 2) + 2) * 68 + j];
    float s3 = simL[((tr << 2) + 3) * 68 + j];
    lk[0][0] += s0*mj.x; lk[0][1] += s0*mj.y; lk[0][2] += s0*mj.z; lk[0][3] += s0*mj.w;
    lk[1][0] += s1*mj.x; lk[1][1] += s1*mj.y; lk[1][2] += s1*mj.z; lk[1][3] += s1*mj.w;
    lk[2][0] += s2*mj.x; lk[2][1] += s2*mj.y; lk[2][2] += s2*mj.z; lk[2][3] += s2*mj.w;
    lk[3][0] += s3*mj.x; lk[3][1] += s3*mj.y; lk[3][2] += s3*mj.z; lk[3][3] += s3*mj.w;
  }
  float* logK = ws + OFF_LOGK;
  #pragma unroll
  for (int i = 0; i < 4; ++i) {
    int row = (tr << 2) + i;
    float4 o = make_float4(lk[i][0]/EPSILON, lk[i][1]/EPSILON, lk[i][2]/EPSILON, lk[i][3]/EPSILON);
    *(float4*)(logK + (size_t)(r0 + row) * 64 + (tc << 2)) = o;
  }
}

// ---------------- K4: one Sinkhorn iteration: u = -lse_row(logK+v); column partials of (logK+u) ----------------
__global__ __launch_bounds__(256) void k4_iter(const float* __restrict__ wsr,
                                               float* __restrict__ ws, int use_v) {
  const float* logK = wsr + OFF_LOGK;
  const float* vg = wsr + OFF_V;
  float* u = ws + OFF_U;
  float* part = ws + OFF_PART;
  __shared__ float vL[64];
  __shared__ float cpm[4][64], cps[4][64];
  int t = threadIdx.x, b = blockIdx.x;
  if (t < 64) vL[t] = use_v ? vg[t] : 0.0f;
  __syncthreads();
  int rloc = t >> 2, q = t & 3;
  int row = b * 64 + rloc;
  const float4* lr = (const float4*)(logK + (size_t)row * 64 + q * 16);
  float4 A0 = lr[0], A1 = lr[1], A2 = lr[2], A3 = lr[3];
  float r[16] = {A0.x,A0.y,A0.z,A0.w, A1.x,A1.y,A1.z,A1.w,
                 A2.x,A2.y,A2.z,A2.w, A3.x,A3.y,A3.z,A3.w};
  // row LSE over 64 cols (16 local + 4 lanes sharing a row)
  float m = -3.402823466e38f;
  #pragma unroll
  for (int i = 0; i < 16; ++i) m = fmaxf(m, r[i] + vL[q * 16 + i]);
  m = fmaxf(m, __shfl_xor(m, 1));
  m = fmaxf(m, __shfl_xor(m, 2));
  float s = 0.f;
  #pragma unroll
  for (int i = 0; i < 16; ++i) s += expf(r[i] + vL[q * 16 + i] - m);
  s += __shfl_xor(s, 1);
  s += __shfl_xor(s, 2);
  float urow = -(m + logf(s));
  if (q == 0) u[row] = urow;
  // column partial LSE of (logK + u) over this wave's 16 rows (lanes with same q, xor 4..32)
  float cm[16], cs[16];
  #pragma unroll
  for (int i = 0; i < 16; ++i) cm[i] = r[i] + urow;
  #pragma unroll
  for (int i = 0; i < 16; ++i) {
    float mm = cm[i];
    mm = fmaxf(mm, __shfl_xor(mm, 4));
    mm = fmaxf(mm, __shfl_xor(mm, 8));
    mm = fmaxf(mm, __shfl_xor(mm, 16));
    mm = fmaxf(mm, __shfl_xor(mm, 32));
    float e = expf(cm[i] - mm);
    e += __shfl_xor(e, 4);
    e += __shfl_xor(e, 8);
    e += __shfl_xor(e, 16);
    e += __shfl_xor(e, 32);
    cm[i] = mm; cs[i] = e;
  }
  int wv = t >> 6, l = t & 63;
  if (l < 4) {  // lane l has q == l; owns cols l*16..l*16+15
    #pragma unroll
    for (int i = 0; i < 16; ++i) { cpm[wv][l*16+i] = cm[i]; cps[wv][l*16+i] = cs[i]; }
  }
  __syncthreads();
  if (t < 64) {
    float M2 = cpm[0][t], S2 = cps[0][t];
    #pragma unroll
    for (int w = 1; w < 4; ++w) {
      float pm = cpm[w][t], ps = cps[w][t];
      float nm = fmaxf(M2, pm);
      S2 = S2 * expf(M2 - nm) + ps * expf(pm - nm);
      M2 = nm;
    }
    part[(size_t)(b * 64 + t) * 2]     = M2;
    part[(size_t)(b * 64 + t) * 2 + 1] = S2;
  }
}

// ---------------- K5: combine column partials -> v ----------------
__global__ __launch_bounds__(256) void k5_combine(const float* __restrict__ wsr,
                                                  float* __restrict__ ws) {
  const float* part = wsr + OFF_PART;
  float* v = ws + OFF_V;
  __shared__ float pm_[4][64], ps_[4][64];
  int t = threadIdx.x;
  int j = t & 63, g = t >> 6;
  float m = -3.402823466e38f, s = 0.0f;
  for (int b = g * 64; b < g * 64 + 64; ++b) {
    float pm = part[(size_t)(b * 64 + j) * 2];
    float ps = part[(size_t)(b * 64 + j) * 2 + 1];
    float nm = fmaxf(m, pm);
    s = s * expf(m - nm) + ps * expf(pm - nm);
    m = nm;
  }
  pm_[g][j] = m; ps_[g][j] = s;
  __syncthreads();
  if (t < 64) {
    float M2 = pm_[0][t], S2 = ps_[0][t];
    #pragma unroll
    for (int w = 1; w < 4; ++w) {
      float pm = pm_[w][t], ps = ps_[w][t];
      float nm = fmaxf(M2, pm);
      S2 = S2 * expf(M2 - nm) + ps * expf(pm - nm);
      M2 = nm;
    }
    v[t] = LOGMASS - (M2 + logf(S2));
  }
}

// ---------------- K7: probs = exp(logK + u + v) ----------------
__global__ __launch_bounds__(256) void k7_final(const float* __restrict__ wsr,
                                                float* __restrict__ out) {
  const float* logK = wsr + OFF_LOGK;
  const float* u = wsr + OFF_U;
  const float* v = wsr + OFF_V;
  int idx = blockIdx.x * 256 + threadIdx.x;
  int e = idx << 2;
  int row = e >> 6, col = e & 63;
  float4 lk = *(const float4*)(logK + e);
  float ur = u[row];
  float4 vv = *(const float4*)(v + col);
  float4 o = make_float4(expf(lk.x + ur + vv.x), expf(lk.y + ur + vv.y),
                         expf(lk.z + ur + vv.z), expf(lk.w + ur + vv.w));
  *(float4*)(out + e) = o;
}

extern "C" void kernel_launch(void* const* d_in, const int* in_sizes, int n_in,
                              void* d_out, int out_size, void* d_ws, size_t ws_size,
                              hipStream_t stream) {
  const float* x  = (const float*)d_in[0];
  const float* ex = (const float*)d_in[1];
  float* out = (float*)d_out;
  float* ws  = (float*)d_ws;

  k1_norm_experts<<<64, 256, 0, stream>>>(ex, ws);
  k2_gram<<<64, 256, 0, stream>>>(ws, ws, out);
  k3_main<<<256, 256, 0, stream>>>(x, ws, ws, out);
  for (int it = 0; it < 5; ++it) {
    k4_iter<<<256, 256, 0, stream>>>(ws, ws, it > 0 ? 1 : 0);
    k5_combine<<<1, 256, 0, stream>>>(ws, ws);
  }
  k7_final<<<1024, 256, 0, stream>>>(ws, out);
}

// Round 3
// 271.744 us; speedup vs baseline: 1.6195x; 1.6195x over previous
//
#include <hip/hip_runtime.h>
#include <math.h>

#define TOKENS 16384
#define EXPERTS 64
#define DIM 2048
#define BETA 0.5f
#define EPSILON 0.05f
#define EPSN 1e-12f
#define LOGMASS 5.545177444479562f  // log(16384/64)

// ws layout (float offsets)
#define OFF_ENORM   0            // 64*2048 fp32 e_norm rows
#define OFF_BBF     131072       // 131072 ushorts (64KB*2): bf16 B in MFMA-fragment order
#define OFF_M       262144       // 64*64
#define OFF_LOGK    266240       // 16384*64
#define OFF_U       1314816      // 16384
#define OFF_V       1331200     // 64
#define OFF_PART    1331264      // 256*64*2
// total 1364032 floats = 5.46 MB (same as round-2, proven to fit ws)

// out layout (float offsets): probs 0, sim 1048576, gram 2097152, gram_off 2101248

typedef __attribute__((ext_vector_type(8))) short short8v;   // 8 bf16 (4 VGPR)
typedef __attribute__((ext_vector_type(4))) float f32x4;

static __device__ __forceinline__ unsigned short f2bf(float f) {
  unsigned int u = __float_as_uint(f);
  u += 0x7FFFu + ((u >> 16) & 1u);   // round-to-nearest-even
  return (unsigned short)(u >> 16);
}

// ---------------- K1: normalize expert rows -> e_norm fp32 + bf16 B-fragment table ----------------
// Bbf layout: flat = (k>>5)*2048 + expert*32 + (k&31)  i.e. [K-block][col][ksub]
__global__ __launch_bounds__(256) void k1_norm_experts(const float* __restrict__ ex,
                                                       float* __restrict__ ws) {
  int j = blockIdx.x, t = threadIdx.x;
  const float4* row4 = (const float4*)(ex + (size_t)j * DIM);
  float4 v0 = row4[t];
  float4 v1 = row4[t + 256];
  float ss = v0.x*v0.x + v0.y*v0.y + v0.z*v0.z + v0.w*v0.w
           + v1.x*v1.x + v1.y*v1.y + v1.z*v1.z + v1.w*v1.w;
  #pragma unroll
  for (int m = 1; m < 64; m <<= 1) ss += __shfl_xor(ss, m);
  __shared__ float red[4];
  int wv = t >> 6, ln = t & 63;
  if (ln == 0) red[wv] = ss;
  __syncthreads();
  float tot = red[0] + red[1] + red[2] + red[3];
  float sc = 1.0f / fmaxf(sqrtf(tot), EPSN);
  float4 w0 = make_float4(v0.x*sc, v0.y*sc, v0.z*sc, v0.w*sc);
  float4 w1 = make_float4(v1.x*sc, v1.y*sc, v1.z*sc, v1.w*sc);
  float4* en4 = (float4*)(ws + OFF_ENORM + (size_t)j * DIM);
  en4[t] = w0;
  en4[t + 256] = w1;
  unsigned short* Bb = (unsigned short*)(ws + OFF_BBF);
  int k0 = t * 4;
  int i0 = ((k0 >> 5) << 11) + (j << 5) + (k0 & 31);
  ushort4 u0; u0.x = f2bf(w0.x); u0.y = f2bf(w0.y); u0.z = f2bf(w0.z); u0.w = f2bf(w0.w);
  *(ushort4*)(Bb + i0) = u0;
  int k1v = (t + 256) * 4;
  int i1 = ((k1v >> 5) << 11) + (j << 5) + (k1v & 31);
  ushort4 u1; u1.x = f2bf(w1.x); u1.y = f2bf(w1.y); u1.z = f2bf(w1.z); u1.w = f2bf(w1.w);
  *(ushort4*)(Bb + i1) = u1;
}

// ---------------- K2: gram, gram_off, M = I - beta*gram_off (fp32, L1-friendly) ----------------
__global__ __launch_bounds__(256) void k2_gram(const float* __restrict__ wsr,
                                               float* __restrict__ ws,
                                               float* __restrict__ out) {
  __shared__ __align__(16) float ej[DIM];
  __shared__ float part[4][64];
  int j = blockIdx.x, t = threadIdx.x;
  const float4* en4 = (const float4*)(wsr + OFF_ENORM + (size_t)j * DIM);
  ((float4*)ej)[t] = en4[t];
  ((float4*)ej)[t + 256] = en4[t + 256];
  __syncthreads();
  int kk = t & 63, q = t >> 6;
  const float4* er = (const float4*)(wsr + OFF_ENORM + (size_t)kk * DIM) + q * 128;
  const float4* ejq = (const float4*)ej + q * 128;
  float p = 0.f;
  #pragma unroll 4
  for (int i = 0; i < 128; ++i) {
    float4 a = ejq[i], b = er[i];
    p += a.x*b.x + a.y*b.y + a.z*b.z + a.w*b.w;
  }
  part[q][kk] = p;
  __syncthreads();
  if (t < 64) {
    float g = part[0][t] + part[1][t] + part[2][t] + part[3][t];
    out[2097152 + j*64 + t] = g;
    float go = fmaxf(g - (t == j ? 1.0f : 0.0f), 0.0f);
    out[2101248 + j*64 + t] = go;
    ws[OFF_M + j*64 + t] = (t == j ? 1.0f : 0.0f) - BETA * go;
  }
}

// ---------------- K3: fused x-norm + sim (bf16 MFMA) + sim@M/eps -> logK ----------------
// 512 blocks x 32 rows, 256 threads (4 waves). Wave w: row-tile (w&1), col-tiles 2*(w>>1), +1.
__global__ __launch_bounds__(256) void k3_main(const float* __restrict__ x,
                                               const float* __restrict__ wsr,
                                               float* __restrict__ ws,
                                               float* __restrict__ out) {
  __shared__ __align__(16) unsigned short A_lds[32 * 64];  // 4KB, XOR-swizzled
  __shared__ __align__(16) float Ml[64 * 64];              // 16KB
  __shared__ __align__(16) float simL[32 * 68];            // 8.7KB
  __shared__ float sqL[32][8];
  __shared__ float scaleL[32];

  const int t = threadIdx.x;
  const int r0 = blockIdx.x * 32;

  // staging map: thread t loads row srow, k-slice sk8..sk8+7 of each 64-wide chunk
  const int srow = t >> 3;
  const int sk8  = (t & 7) << 3;
  const float* xrow = x + (size_t)(r0 + srow) * DIM + sk8;
  char* Ab = (char*)A_lds;
  const int wbyte = (srow * 128 + ((t & 7) << 4)) ^ ((srow & 7) << 4);

  // MFMA map
  const int l = t & 63, w = t >> 6;
  const int rw = w & 1;
  const int tcA = (w >> 1) << 1;            // col-tiles tcA, tcA+1
  const int arow = rw * 16 + (l & 15);
  const int abyte0 = (arow * 128 + ((l >> 4) << 4)) ^ ((arow & 7) << 4);
  const int abyte1 = (arow * 128 + ((4 + (l >> 4)) << 4)) ^ ((arow & 7) << 4);
  const unsigned short* Bws = (const unsigned short*)(wsr + OFF_BBF);
  const int boffA = ((tcA * 16 + (l & 15)) << 5) + ((l >> 4) << 3);
  const int boffB = boffA + (16 << 5);

  f32x4 acc0 = {0.f, 0.f, 0.f, 0.f};
  f32x4 acc1 = {0.f, 0.f, 0.f, 0.f};
  float nsq = 0.f;

  // prefetch chunk 0 (8 floats/thread)
  float4 a0 = *(const float4*)xrow;
  float4 a1 = *(const float4*)(xrow + 4);

  for (int c = 0; c < 32; ++c) {
    float4 c0 = a0, c1 = a1;
    if (c < 31) {                       // prefetch next chunk (hides HBM latency)
      const float* nx = xrow + (c + 1) * 64;
      a0 = *(const float4*)nx;
      a1 = *(const float4*)(nx + 4);
    }
    // B fragments for this chunk (L2-resident, fragment-order table)
    const unsigned short* bp = Bws + (size_t)(c * 2) * 2048;
    short8v b00 = *(const short8v*)(bp + boffA);
    short8v b01 = *(const short8v*)(bp + boffB);
    short8v b10 = *(const short8v*)(bp + 2048 + boffA);
    short8v b11 = *(const short8v*)(bp + 2048 + boffB);

    nsq += c0.x*c0.x + c0.y*c0.y + c0.z*c0.z + c0.w*c0.w
         + c1.x*c1.x + c1.y*c1.y + c1.z*c1.z + c1.w*c1.w;
    short8v av;
    av[0] = (short)f2bf(c0.x); av[1] = (short)f2bf(c0.y);
    av[2] = (short)f2bf(c0.z); av[3] = (short)f2bf(c0.w);
    av[4] = (short)f2bf(c1.x); av[5] = (short)f2bf(c1.y);
    av[6] = (short)f2bf(c1.z); av[7] = (short)f2bf(c1.w);
    *(short8v*)(Ab + wbyte) = av;
    __syncthreads();
    short8v af0 = *(const short8v*)(Ab + abyte0);
    short8v af1 = *(const short8v*)(Ab + abyte1);
    acc0 = __builtin_amdgcn_mfma_f32_16x16x32_bf16(af0, b00, acc0, 0, 0, 0);
    acc1 = __builtin_amdgcn_mfma_f32_16x16x32_bf16(af0, b01, acc1, 0, 0, 0);
    acc0 = __builtin_amdgcn_mfma_f32_16x16x32_bf16(af1, b10, acc0, 0, 0, 0);
    acc1 = __builtin_amdgcn_mfma_f32_16x16x32_bf16(af1, b11, acc1, 0, 0, 0);
    __syncthreads();
  }

  // row norms + load M
  sqL[srow][t & 7] = nsq;
  {
    const float4* Mw = (const float4*)(wsr + OFF_M);
    float4* Ml4 = (float4*)Ml;
    #pragma unroll
    for (int s = 0; s < 4; ++s) Ml4[s * 256 + t] = Mw[s * 256 + t];
  }
  __syncthreads();
  if (t < 32) {
    float tot = 0.f;
    #pragma unroll
    for (int i = 0; i < 8; ++i) tot += sqL[t][i];
    scaleL[t] = 1.0f / fmaxf(sqrtf(tot), EPSN);
  }
  __syncthreads();

  // sim = acc * (1/||x||): C/D layout col=lane&15, row=(lane>>4)*4+reg
  float* simOut = out + 1048576;
  const int colA = tcA * 16 + (l & 15);
  #pragma unroll
  for (int j = 0; j < 4; ++j) {
    int rr = rw * 16 + ((l >> 4) << 2) + j;
    float sc = scaleL[rr];
    float s0 = acc0[j] * sc, s1 = acc1[j] * sc;
    simL[rr * 68 + colA]      = s0;
    simL[rr * 68 + colA + 16] = s1;
    simOut[(size_t)(r0 + rr) * 64 + colA]      = s0;
    simOut[(size_t)(r0 + rr) * 64 + colA + 16] = s1;
  }
  __syncthreads();

  // logK = (sim @ M) / eps  (fp32)
  const int tr = t >> 4, tc = t & 15;
  float lk0[4] = {0.f,0.f,0.f,0.f}, lk1[4] = {0.f,0.f,0.f,0.f};
  #pragma unroll 8
  for (int j = 0; j < 64; ++j) {
    float4 mj = *(const float4*)&Ml[j * 64 + (tc << 2)];
    float s0 = simL[(tr * 2) * 68 + j];
    float s1 = simL[(tr * 2 + 1) * 68 + j];
    lk0[0] += s0*mj.x; lk0[1] += s0*mj.y; lk0[2] += s0*mj.z; lk0[3] += s0*mj.w;
    lk1[0] += s1*mj.x; lk1[1] += s1*mj.y; lk1[2] += s1*mj.z; lk1[3] += s1*mj.w;
  }
  float* logK = ws + OFF_LOGK;
  const float ie = 1.0f / EPSILON;
  float4 o0 = make_float4(lk0[0]*ie, lk0[1]*ie, lk0[2]*ie, lk0[3]*ie);
  float4 o1 = make_float4(lk1[0]*ie, lk1[1]*ie, lk1[2]*ie, lk1[3]*ie);
  *(float4*)(logK + (size_t)(r0 + tr*2    ) * 64 + (tc << 2)) = o0;
  *(float4*)(logK + (size_t)(r0 + tr*2 + 1) * 64 + (tc << 2)) = o1;
}

// ---------------- K4: one Sinkhorn iteration ----------------
__global__ __launch_bounds__(256) void k4_iter(const float* __restrict__ wsr,
                                               float* __restrict__ ws, int use_v) {
  const float* logK = wsr + OFF_LOGK;
  const float* vg = wsr + OFF_V;
  float* u = ws + OFF_U;
  float* part = ws + OFF_PART;
  __shared__ float vL[64];
  __shared__ float cpm[4][64], cps[4][64];
  int t = threadIdx.x, b = blockIdx.x;
  if (t < 64) vL[t] = use_v ? vg[t] : 0.0f;
  __syncthreads();
  int rloc = t >> 2, q = t & 3;
  int row = b * 64 + rloc;
  const float4* lr = (const float4*)(logK + (size_t)row * 64 + q * 16);
  float4 A0 = lr[0], A1 = lr[1], A2 = lr[2], A3 = lr[3];
  float r[16] = {A0.x,A0.y,A0.z,A0.w, A1.x,A1.y,A1.z,A1.w,
                 A2.x,A2.y,A2.z,A2.w, A3.x,A3.y,A3.z,A3.w};
  float m = -3.402823466e38f;
  #pragma unroll
  for (int i = 0; i < 16; ++i) m = fmaxf(m, r[i] + vL[q * 16 + i]);
  m = fmaxf(m, __shfl_xor(m, 1));
  m = fmaxf(m, __shfl_xor(m, 2));
  float s = 0.f;
  #pragma unroll
  for (int i = 0; i < 16; ++i) s += __expf(r[i] + vL[q * 16 + i] - m);
  s += __shfl_xor(s, 1);
  s += __shfl_xor(s, 2);
  float urow = -(m + __logf(s));
  if (q == 0) u[row] = urow;
  float cm[16], cs[16];
  #pragma unroll
  for (int i = 0; i < 16; ++i) cm[i] = r[i] + urow;
  #pragma unroll
  for (int i = 0; i < 16; ++i) {
    float mm = cm[i];
    mm = fmaxf(mm, __shfl_xor(mm, 4));
    mm = fmaxf(mm, __shfl_xor(mm, 8));
    mm = fmaxf(mm, __shfl_xor(mm, 16));
    mm = fmaxf(mm, __shfl_xor(mm, 32));
    float e = __expf(cm[i] - mm);
    e += __shfl_xor(e, 4);
    e += __shfl_xor(e, 8);
    e += __shfl_xor(e, 16);
    e += __shfl_xor(e, 32);
    cm[i] = mm; cs[i] = e;
  }
  int wv = t >> 6, ll = t & 63;
  if (ll < 4) {
    #pragma unroll
    for (int i = 0; i < 16; ++i) { cpm[wv][ll*16+i] = cm[i]; cps[wv][ll*16+i] = cs[i]; }
  }
  __syncthreads();
  if (t < 64) {
    float M2 = cpm[0][t], S2 = cps[0][t];
    #pragma unroll
    for (int w2 = 1; w2 < 4; ++w2) {
      float pm = cpm[w2][t], ps = cps[w2][t];
      float nm = fmaxf(M2, pm);
      S2 = S2 * __expf(M2 - nm) + ps * __expf(pm - nm);
      M2 = nm;
    }
    part[(size_t)(b * 64 + t) * 2]     = M2;
    part[(size_t)(b * 64 + t) * 2 + 1] = S2;
  }
}

// ---------------- K5: combine column partials -> v (batched loads) ----------------
__global__ __launch_bounds__(256) void k5_combine(const float* __restrict__ wsr,
                                                  float* __restrict__ ws) {
  const float* part = wsr + OFF_PART;
  float* v = ws + OFF_V;
  __shared__ float pm_[4][64], ps_[4][64];
  int t = threadIdx.x;
  int j = t & 63, g = t >> 6;
  float m = -3.402823466e38f, s = 0.0f;
  for (int b0 = g * 64; b0 < g * 64 + 64; b0 += 8) {
    float pm[8], ps[8];
    #pragma unroll
    for (int i = 0; i < 8; ++i) {
      pm[i] = part[(size_t)((b0 + i) * 64 + j) * 2];
      ps[i] = part[(size_t)((b0 + i) * 64 + j) * 2 + 1];
    }
    #pragma unroll
    for (int i = 0; i < 8; ++i) {
      float nm = fmaxf(m, pm[i]);
      s = s * __expf(m - nm) + ps[i] * __expf(pm[i] - nm);
      m = nm;
    }
  }
  pm_[g][j] = m; ps_[g][j] = s;
  __syncthreads();
  if (t < 64) {
    float M2 = pm_[0][t], S2 = ps_[0][t];
    #pragma unroll
    for (int w = 1; w < 4; ++w) {
      float pm = pm_[w][t], ps = ps_[w][t];
      float nm = fmaxf(M2, pm);
      S2 = S2 * __expf(M2 - nm) + ps * __expf(pm - nm);
      M2 = nm;
    }
    v[t] = LOGMASS - (M2 + __logf(S2));
  }
}

// ---------------- K7: probs = exp(logK + u + v) ----------------
__global__ __launch_bounds__(256) void k7_final(const float* __restrict__ wsr,
                                                float* __restrict__ out) {
  const float* logK = wsr + OFF_LOGK;
  const float* u = wsr + OFF_U;
  const float* v = wsr + OFF_V;
  int idx = blockIdx.x * 256 + threadIdx.x;
  int e = idx << 2;
  int row = e >> 6, col = e & 63;
  float4 lk = *(const float4*)(logK + e);
  float ur = u[row];
  float4 vv = *(const float4*)(v + col);
  float4 o = make_float4(__expf(lk.x + ur + vv.x), __expf(lk.y + ur + vv.y),
                         __expf(lk.z + ur + vv.z), __expf(lk.w + ur + vv.w));
  *(float4*)(out + e) = o;
}

extern "C" void kernel_launch(void* const* d_in, const int* in_sizes, int n_in,
                              void* d_out, int out_size, void* d_ws, size_t ws_size,
                              hipStream_t stream) {
  const float* x  = (const float*)d_in[0];
  const float* ex = (const float*)d_in[1];
  float* out = (float*)d_out;
  float* ws  = (float*)d_ws;

  k1_norm_experts<<<64, 256, 0, stream>>>(ex, ws);
  k2_gram<<<64, 256, 0, stream>>>(ws, ws, out);
  k3_main<<<512, 256, 0, stream>>>(x, ws, ws, out);
  for (int it = 0; it < 5; ++it) {
    k4_iter<<<256, 256, 0, stream>>>(ws, ws, it > 0 ? 1 : 0);
    k5_combine<<<1, 256, 0, stream>>>(ws, ws);
  }
  k7_final<<<1024, 256, 0, stream>>>(ws, out);
}